// Round 3
// baseline (62757.733 us; speedup 1.0000x reference)
//
#include <hip/hip_runtime.h>
#include <hip/hip_bf16.h>

#define VOCAB  32000
#define DIM    1024
#define NLAYER 4
#define NB     8
#define SEQ    512

#define SCAN_BLOCKS  256
#define SCAN_THREADS 512
#define ROWS_PER_BLK 4   // 1024 gate/cand rows / 256 blocks

typedef __attribute__((ext_vector_type(8))) short          bf16x8;
typedef __attribute__((ext_vector_type(4))) float          f32x4;
typedef __attribute__((ext_vector_type(8))) unsigned short u16x8;

__device__ __forceinline__ float fma4(float4 a, float4 b, float acc) {
    acc = fmaf(a.x, b.x, acc);
    acc = fmaf(a.y, b.y, acc);
    acc = fmaf(a.z, b.z, acc);
    acc = fmaf(a.w, b.w, acc);
    return acc;
}

__device__ __forceinline__ u16x8 cvt8_bf16(const float* p) {
    float4 f0 = *(const float4*)p;
    float4 f1 = *(const float4*)(p + 4);
    union { __hip_bfloat16 h[8]; u16x8 v; } u;
    u.h[0] = __float2bfloat16(f0.x); u.h[1] = __float2bfloat16(f0.y);
    u.h[2] = __float2bfloat16(f0.z); u.h[3] = __float2bfloat16(f0.w);
    u.h[4] = __float2bfloat16(f1.x); u.h[5] = __float2bfloat16(f1.y);
    u.h[6] = __float2bfloat16(f1.z); u.h[7] = __float2bfloat16(f1.w);
    return u.v;
}

// ---------------------------------------------------------------------------
// Zero the barrier block (must run before gru_scan each call: counters are
// monotonic within a call and the harness does not re-poison ws between
// graph replays).
// ---------------------------------------------------------------------------
__global__ void bar_init_kernel(unsigned* __restrict__ bar) {
    bar[threadIdx.x] = 0u;   // 1024 words = 4 KiB
}

// ---------------------------------------------------------------------------
// Two-level monotonic grid barrier, SYSTEM-scope atomics (strongest cache
// ops: L2 writeback on release, L1/L2 invalidate on acquire — safe across
// XCDs). Entry __syncthreads drains each wave's vmcnt, so all block stores
// are in L2 before thread 0's release; wb/inv cache ops act cache-wide, so
// thread 0's fence covers the whole block's writes.
// Monotonic: episode ep needs leaf == ep*32, root == ep*8. Timeout ~40ms
// (legit waits are <100us); on timeout we mark dead and the kernel tail
// writes a 1e8 sentinel so the failure is unmistakable in absmax.
// ---------------------------------------------------------------------------
__device__ __forceinline__ void gbar(unsigned* bar, unsigned& ep, bool& dead) {
    __syncthreads();
    if (threadIdx.x == 0 && !dead) {
        unsigned* root = bar;
        unsigned* leaf = bar + 32 + 32 * (blockIdx.x & 7);
        unsigned old = __hip_atomic_fetch_add(leaf, 1u, __ATOMIC_ACQ_REL,
                                              __HIP_MEMORY_SCOPE_SYSTEM);
        if (old == ep * (SCAN_BLOCKS / 8) - 1)
            __hip_atomic_fetch_add(root, 1u, __ATOMIC_ACQ_REL,
                                   __HIP_MEMORY_SCOPE_SYSTEM);
        unsigned guard = 0;
        while (__hip_atomic_load(root, __ATOMIC_RELAXED,
                                 __HIP_MEMORY_SCOPE_SYSTEM) < ep * 8u) {
            __builtin_amdgcn_s_sleep(8);
            if (++guard > (1u << 17)) { dead = true; break; }
        }
        // single acquire to invalidate caches before consuming peer data
        (void)__hip_atomic_load(root, __ATOMIC_ACQUIRE,
                                __HIP_MEMORY_SCOPE_SYSTEM);
    }
    __syncthreads();
    ep++;
}

// ---------------------------------------------------------------------------
// GRU scan: 256 blocks x 512 threads. Block bk owns gate rows
// j in [bk*4, bk*4+4); 2 waves per row split the 8 batches 4/4.
// Per (t, layer): stage xin,h -> LDS; Phase A computes z,r,candA (z/candA
// stay in registers across the barrier, r round-trips through global);
// gbar; stage r -> LDS; Phase B candB + state update; gbar.
// ---------------------------------------------------------------------------
__global__ void __launch_bounds__(SCAN_THREADS, 2) gru_scan(
    const int*   __restrict__ ids,     // [NB][SEQ]
    const float* __restrict__ embW,    // [VOCAB][DIM]
    const float* __restrict__ hstart,  // [NLAYER][DIM]
    const float* __restrict__ gW,      // [NLAYER][2*DIM][2*DIM]
    const float* __restrict__ gB,      // [NLAYER][2*DIM]
    const float* __restrict__ cW,      // [NLAYER][DIM][2*DIM]
    const float* __restrict__ cB,      // [NLAYER][DIM]
    float* __restrict__ hbuf,          // [2][NLAYER][NB][DIM]
    float* __restrict__ rbuf,          // [NB][DIM]
    float* __restrict__ ysf,           // [NB][SEQ][DIM] fp32
    unsigned* __restrict__ bar)
{
    __shared__ float lx[NB][DIM];      // xin (phase A) / r (phase B)
    __shared__ float lh[NB][DIM];      // old h

    const int tid  = threadIdx.x;
    const int lane = tid & 63;
    const int wv   = tid >> 6;                               // 0..7
    const int j    = blockIdx.x * ROWS_PER_BLK + (wv >> 1);  // 0..1023
    const int b0   = (wv & 1) * 4;

    unsigned ep = 1;
    bool dead = false;

    // init h parity-0 buffer: hbuf[0][layer][b][d] = hstart[layer][d]
    {
        int g = blockIdx.x * SCAN_THREADS + tid;
        if (g < NLAYER * NB * DIM)
            hbuf[g] = hstart[((g >> 13) << 10) | (g & (DIM - 1))];
    }
    gbar(bar, ep, dead);

    for (int t = 0; t < SEQ; ++t) {
        const float* hR  = hbuf + (t & 1)       * (NLAYER * NB * DIM);
        float*       hWp = hbuf + ((t & 1) ^ 1) * (NLAYER * NB * DIM);

        for (int layer = 0; layer < NLAYER; ++layer) {
            // ---- stage xin and old h into LDS (coalesced float4) ----
            if (layer == 0) {
                int rows[NB];
                #pragma unroll
                for (int b = 0; b < NB; ++b) rows[b] = ids[b * SEQ + t];
                #pragma unroll
                for (int q = 0; q < 4; ++q) {
                    int e = q * SCAN_THREADS + tid;          // 0..2047 float4
                    int b = e >> 8, c4 = e & 255;
                    ((float4*)&lx[0][0])[e] =
                        ((const float4*)(embW + (size_t)rows[b] * DIM))[c4];
                }
            } else {
                const float* src = hWp + (layer - 1) * NB * DIM;
                #pragma unroll
                for (int q = 0; q < 4; ++q) {
                    int e = q * SCAN_THREADS + tid;
                    ((float4*)&lx[0][0])[e] = ((const float4*)src)[e];
                }
            }
            {
                const float* src = hR + layer * NB * DIM;
                #pragma unroll
                for (int q = 0; q < 4; ++q) {
                    int e = q * SCAN_THREADS + tid;
                    ((float4*)&lh[0][0])[e] = ((const float4*)src)[e];
                }
            }
            __syncthreads();

            // ---- Phase A: z, r, candA for row j, batches b0..b0+3 ----
            const float* wz = gW + ((size_t)layer * 2048 + j) * 2048;
            const float* wr = wz + (size_t)1024 * 2048;
            const float* wc = cW + ((size_t)layer * 1024 + j) * 2048;

            float az[4] = {0.f, 0.f, 0.f, 0.f};
            float ar[4] = {0.f, 0.f, 0.f, 0.f};
            float ac[4] = {0.f, 0.f, 0.f, 0.f};

            #pragma unroll
            for (int it = 0; it < 4; ++it) {
                const int k0 = it * 256 + lane * 4;
                const float4 z4 = *(const float4*)(wz + k0);
                const float4 r4 = *(const float4*)(wr + k0);
                const float4 c4 = *(const float4*)(wc + k0);
                #pragma unroll
                for (int bb = 0; bb < 4; ++bb) {
                    const float4 x4 = *(const float4*)&lx[b0 + bb][k0];
                    az[bb] = fma4(z4, x4, az[bb]);
                    ar[bb] = fma4(r4, x4, ar[bb]);
                    ac[bb] = fma4(c4, x4, ac[bb]);
                }
            }
            #pragma unroll
            for (int it = 0; it < 4; ++it) {
                const int k0 = it * 256 + lane * 4;
                const float4 z4 = *(const float4*)(wz + 1024 + k0);
                const float4 r4 = *(const float4*)(wr + 1024 + k0);
                #pragma unroll
                for (int bb = 0; bb < 4; ++bb) {
                    const float4 h4 = *(const float4*)&lh[b0 + bb][k0];
                    az[bb] = fma4(z4, h4, az[bb]);
                    ar[bb] = fma4(r4, h4, ar[bb]);
                }
            }
            #pragma unroll
            for (int bb = 0; bb < 4; ++bb) {
                #pragma unroll
                for (int off = 32; off > 0; off >>= 1) {
                    az[bb] += __shfl_xor(az[bb], off);
                    ar[bb] += __shfl_xor(ar[bb], off);
                    ac[bb] += __shfl_xor(ac[bb], off);
                }
            }
            const float bz = gB[layer * 2048 + j];
            const float br = gB[layer * 2048 + 1024 + j];
            float zg[4], rg[4];
            #pragma unroll
            for (int bb = 0; bb < 4; ++bb) {
                zg[bb] = 1.f / (1.f + expf(-(az[bb] + bz)));
                rg[bb] = 1.f / (1.f + expf(-(ar[bb] + br)));
            }
            if (lane == 0) {
                rbuf[(b0 + 0) * DIM + j] = rg[0];
                rbuf[(b0 + 1) * DIM + j] = rg[1];
                rbuf[(b0 + 2) * DIM + j] = rg[2];
                rbuf[(b0 + 3) * DIM + j] = rg[3];
            }
            gbar(bar, ep, dead);

            // ---- stage r into LDS (over xin slot) ----
            #pragma unroll
            for (int q = 0; q < 4; ++q) {
                int e = q * SCAN_THREADS + tid;
                ((float4*)&lx[0][0])[e] = ((const float4*)rbuf)[e];
            }
            __syncthreads();

            // ---- Phase B: candB + update ----
            float ab[4] = {0.f, 0.f, 0.f, 0.f};
            #pragma unroll
            for (int it = 0; it < 4; ++it) {
                const int k0 = it * 256 + lane * 4;
                const float4 w4 = *(const float4*)(wc + 1024 + k0);
                #pragma unroll
                for (int bb = 0; bb < 4; ++bb) {
                    const float4 r4 = *(const float4*)&lx[b0 + bb][k0];
                    const float4 h4 = *(const float4*)&lh[b0 + bb][k0];
                    float4 p;
                    p.x = r4.x * h4.x; p.y = r4.y * h4.y;
                    p.z = r4.z * h4.z; p.w = r4.w * h4.w;
                    ab[bb] = fma4(w4, p, ab[bb]);
                }
            }
            #pragma unroll
            for (int bb = 0; bb < 4; ++bb)
                #pragma unroll
                for (int off = 32; off > 0; off >>= 1)
                    ab[bb] += __shfl_xor(ab[bb], off);

            if (lane == 0) {
                const float cbias = cB[layer * DIM + j];
                #pragma unroll
                for (int bb = 0; bb < 4; ++bb) {
                    const int b = b0 + bb;
                    const float cand = tanhf(ac[bb] + ab[bb] + cbias);
                    const float hold = lh[b][j];
                    const float hn   = zg[bb] * hold + (1.f - zg[bb]) * cand;
                    hWp[(layer * NB + b) * DIM + j] = hn;
                    if (layer == NLAYER - 1)
                        ysf[((size_t)b * SEQ + t) * DIM + j] = hn;
                }
            }
            gbar(bar, ep, dead);
        }
    }

    // barrier-death sentinel: make the failure mode unmistakable
    if (dead && threadIdx.x == 0)
        ysf[blockIdx.x] = 1.0e8f;
}

// ---------------------------------------------------------------------------
// Logits GEMM: C[m][n] = sum_k ys[m][k] * outW[n][k]
// M=4096, N=32000, K=1024. Both A (ysf) and B (out_W) are fp32 in HBM,
// converted to bf16 during LDS staging. 128x128 tile, BK=64, 4 waves,
// mfma_f32_16x16x32_bf16, fp32 accumulate.
// ---------------------------------------------------------------------------
#define BM 128
#define BN 128
#define BK 64

__global__ void __launch_bounds__(256) out_gemm(
    const float* __restrict__ A,   // [4096][1024]  fp32
    const float* __restrict__ B,   // [32000][1024] fp32
    float* __restrict__ C)         // [4096][32000]
{
    __shared__ __hip_bfloat16 At[BM][BK + 8];
    __shared__ __hip_bfloat16 Bt[BN][BK + 8];

    const int tid  = threadIdx.x;
    const int lane = tid & 63;
    const int wv   = tid >> 6;
    const int wm   = wv >> 1, wn = wv & 1;
    const int m0   = blockIdx.y * BM;
    const int n0   = blockIdx.x * BN;

    f32x4 acc[4][4];
    #pragma unroll
    for (int i = 0; i < 4; ++i)
        #pragma unroll
        for (int jj = 0; jj < 4; ++jj)
            acc[i][jj] = (f32x4){0.f, 0.f, 0.f, 0.f};

    const int srow = tid >> 3;           // 0..31
    const int scol = (tid & 7) * 8;      // 0..56
    const int l15  = lane & 15;
    const int l4   = lane >> 4;

    for (int kt = 0; kt < DIM / BK; ++kt) {
        const int k0 = kt * BK;
        #pragma unroll
        for (int rnd = 0; rnd < 4; ++rnd) {
            const int row = rnd * 32 + srow;
            *(u16x8*)&At[row][scol] =
                cvt8_bf16(&A[(size_t)(m0 + row) * DIM + k0 + scol]);
            *(u16x8*)&Bt[row][scol] =
                cvt8_bf16(&B[(size_t)(n0 + row) * DIM + k0 + scol]);
        }
        __syncthreads();
        #pragma unroll
        for (int ks = 0; ks < 2; ++ks) {
            bf16x8 av[4], bv[4];
            #pragma unroll
            for (int i = 0; i < 4; ++i) {
                av[i] = *(const bf16x8*)&At[wm * 64 + i * 16 + l15][ks * 32 + l4 * 8];
                bv[i] = *(const bf16x8*)&Bt[wn * 64 + i * 16 + l15][ks * 32 + l4 * 8];
            }
            #pragma unroll
            for (int i = 0; i < 4; ++i)
                #pragma unroll
                for (int jj = 0; jj < 4; ++jj)
                    acc[i][jj] = __builtin_amdgcn_mfma_f32_16x16x32_bf16(
                        av[i], bv[jj], acc[i][jj], 0, 0, 0);
        }
        __syncthreads();
    }

    // epilogue: C/D layout col = lane&15, row = (lane>>4)*4 + reg
    const int rq = l4 * 4;
    #pragma unroll
    for (int i = 0; i < 4; ++i) {
        const int rbase = m0 + wm * 64 + i * 16 + rq;
        #pragma unroll
        for (int jj = 0; jj < 4; ++jj) {
            const int col = n0 + wn * 64 + jj * 16 + l15;
            #pragma unroll
            for (int r2 = 0; r2 < 4; ++r2)
                C[(size_t)(rbase + r2) * VOCAB + col] = acc[i][jj][r2];
        }
    }
}

// ---------------------------------------------------------------------------
extern "C" void kernel_launch(void* const* d_in, const int* in_sizes, int n_in,
                              void* d_out, int out_size, void* d_ws, size_t ws_size,
                              hipStream_t stream)
{
    (void)in_sizes; (void)n_in; (void)out_size; (void)ws_size;
    const int*   ids  = (const int*)  d_in[0];
    const float* embW = (const float*)d_in[1];
    const float* hst  = (const float*)d_in[2];
    const float* gW   = (const float*)d_in[3];
    const float* gB   = (const float*)d_in[4];
    const float* cW   = (const float*)d_in[5];
    const float* cB   = (const float*)d_in[6];
    const float* outW = (const float*)d_in[7];
    float* logits = (float*)d_out;

    // workspace carve-up (total ~16.6 MiB)
    char* ws = (char*)d_ws;
    unsigned* bar  = (unsigned*)ws;                     // 4 KiB
    float*    rbuf = (float*)(ws + 4096);               // 32 KiB
    float*    hbuf = (float*)(ws + 4096 + 32768);       // 256 KiB
    float*    ysf  = (float*)(ws + 4096 + 32768 + 262144);   // 16 MiB

    // 1) zero barrier counters (stream-ordered before the scan)
    bar_init_kernel<<<dim3(1), dim3(1024), 0, stream>>>(bar);

    // 2) GRU scan (normal launch; manual system-scope grid barrier)
    gru_scan<<<dim3(SCAN_BLOCKS), dim3(SCAN_THREADS), 0, stream>>>(
        ids, embW, hst, gW, gB, cW, cB, hbuf, rbuf, ysf, bar);

    // 3) logits GEMM (fp32 inputs, bf16 conversion in LDS staging)
    out_gemm<<<dim3(VOCAB / BN, (NB * SEQ) / BM), dim3(256), 0, stream>>>(ysf, outW, logits);
}